// Round 8
// baseline (348.211 us; speedup 1.0000x reference)
//
#include <hip/hip_runtime.h>

#define HH 448
#define WW 512
#define NPIX (HH * WW)

struct Res { int idx; float ent; };

__device__ __forceinline__ float lrelu(float v) { return v > 0.0f ? v : 0.01f * v; }

__device__ __forceinline__ Res argmax_ent16(const float* __restrict__ v) {
    float m = v[0]; int idx = 0;
#pragma unroll
    for (int i = 1; i < 16; i++) { if (v[i] > m) { m = v[i]; idx = i; } }
    float s = 0.0f, dot = 0.0f;
#pragma unroll
    for (int i = 0; i < 16; i++) {
        float t = __expf(v[i] - m);
        s += t;
        dot = fmaf(t, v[i], dot);
    }
    Res r; r.idx = idx; r.ent = m + __logf(s) - dot / s;
    return r;
}

// exchange 16 half-outputs with partner lane (lane^1) -> full 32-vector
__device__ __forceinline__ void exchange16(int half, const float* __restrict__ yh,
                                           float* __restrict__ xfull) {
#pragma unroll
    for (int k = 0; k < 16; k++) {
        float o = __shfl_xor(yh[k], 1, 64);
        xfull[k]      = half ? o     : yh[k];
        xfull[16 + k] = half ? yh[k] : o;
    }
}

// exchange 8 half-logits -> full 16-vector
__device__ __forceinline__ void exchange8(int half, const float* __restrict__ zh,
                                          float* __restrict__ z16) {
#pragma unroll
    for (int k = 0; k < 8; k++) {
        float o = __shfl_xor(zh[k], 1, 64);
        z16[k]     = half ? o     : zh[k];
        z16[8 + k] = half ? zh[k] : o;
    }
}

// stage-1 layer, weight layout [OUT=32][in=32]; lane computes outs half*16..+15
__device__ __forceinline__ void layer_oi_h32(const float* __restrict__ w,
                                             const float* __restrict__ b, int half,
                                             const float* __restrict__ x,
                                             float* __restrict__ y) {
#pragma unroll
    for (int k = 0; k < 16; k++) {
        int o = half * 16 + k;
        const float4* row = (const float4*)(w + o * 32);
        float a = b[o];
#pragma unroll
        for (int q = 0; q < 8; q++) {
            float4 wv = row[q];
            a = fmaf(wv.x, x[4 * q + 0], a);
            a = fmaf(wv.y, x[4 * q + 1], a);
            a = fmaf(wv.z, x[4 * q + 2], a);
            a = fmaf(wv.w, x[4 * q + 3], a);
        }
        y[k] = a;
    }
}

// stage-1 final layer [16][32]; lane computes outs half*8..+7
__device__ __forceinline__ void layer_oi_h16(const float* __restrict__ w,
                                             const float* __restrict__ b, int half,
                                             const float* __restrict__ x,
                                             float* __restrict__ y) {
#pragma unroll
    for (int k = 0; k < 8; k++) {
        int o = half * 8 + k;
        const float4* row = (const float4*)(w + o * 32);
        float a = b[o];
#pragma unroll
        for (int q = 0; q < 8; q++) {
            float4 wv = row[q];
            a = fmaf(wv.x, x[4 * q + 0], a);
            a = fmaf(wv.y, x[4 * q + 1], a);
            a = fmaf(wv.z, x[4 * q + 2], a);
            a = fmaf(wv.w, x[4 * q + 3], a);
        }
        y[k] = a;
    }
}

// stage-2/3 layer, weight layout [in=32][out=32]; lane computes out-cols half*16..+15
__device__ __forceinline__ void layer_io_h32(const float* __restrict__ w,
                                             const float* __restrict__ b, int half,
                                             const float* __restrict__ x,
                                             float* __restrict__ y) {
    float acc[16];
#pragma unroll
    for (int k = 0; k < 16; k++) acc[k] = b[half * 16 + k];
#pragma unroll
    for (int i = 0; i < 32; i++) {
        const float4* row = (const float4*)(w + i * 32 + half * 16);
        float xi = x[i];
#pragma unroll
        for (int q = 0; q < 4; q++) {
            float4 wv = row[q];
            acc[4 * q + 0] = fmaf(xi, wv.x, acc[4 * q + 0]);
            acc[4 * q + 1] = fmaf(xi, wv.y, acc[4 * q + 1]);
            acc[4 * q + 2] = fmaf(xi, wv.z, acc[4 * q + 2]);
            acc[4 * q + 3] = fmaf(xi, wv.w, acc[4 * q + 3]);
        }
    }
#pragma unroll
    for (int k = 0; k < 16; k++) y[k] = acc[k];
}

// stage-2/3 final layer [32][16]; lane computes out-cols half*8..+7
__device__ __forceinline__ void layer_io_h16(const float* __restrict__ w,
                                             const float* __restrict__ b, int half,
                                             const float* __restrict__ x,
                                             float* __restrict__ y) {
    float acc[8];
#pragma unroll
    for (int k = 0; k < 8; k++) acc[k] = b[half * 8 + k];
#pragma unroll
    for (int i = 0; i < 32; i++) {
        const float4* row = (const float4*)(w + i * 16 + half * 8);
        float xi = x[i];
#pragma unroll
        for (int q = 0; q < 2; q++) {
            float4 wv = row[q];
            acc[4 * q + 0] = fmaf(xi, wv.x, acc[4 * q + 0]);
            acc[4 * q + 1] = fmaf(xi, wv.y, acc[4 * q + 1]);
            acc[4 * q + 2] = fmaf(xi, wv.z, acc[4 * q + 2]);
            acc[4 * q + 3] = fmaf(xi, wv.w, acc[4 * q + 3]);
        }
    }
#pragma unroll
    for (int k = 0; k < 8; k++) y[k] = acc[k];
}

// two-lane expert MLP 32->32->32->16 (stages 2/3); both lanes return identical Res
__device__ __forceinline__ Res expert_mlp_half(const float* __restrict__ xb, int p, int half,
                                               const float* __restrict__ w0, const float* __restrict__ b0,
                                               const float* __restrict__ w1, const float* __restrict__ b1,
                                               const float* __restrict__ w2, const float* __restrict__ b2,
                                               size_t e) {
    float xfull[32];
#pragma unroll
    for (int c = 0; c < 32; c++) xfull[c] = xb[(size_t)c * NPIX + p];
    float yh[16];
    layer_io_h32(w0 + e * 1024, b0 + e * 32, half, xfull, yh);
#pragma unroll
    for (int k = 0; k < 16; k++) yh[k] = lrelu(yh[k]);
    exchange16(half, yh, xfull);
    layer_io_h32(w1 + e * 1024, b1 + e * 32, half, xfull, yh);
#pragma unroll
    for (int k = 0; k < 16; k++) yh[k] = lrelu(yh[k]);
    exchange16(half, yh, xfull);
    float zh[8];
    layer_io_h16(w2 + e * 512, b2 + e * 16, half, xfull, zh);
    float z[16];
    exchange8(half, zh, z);
    return argmax_ent16(z);
}

__global__ __launch_bounds__(256, 6) void cls3_kernel(
    const float* __restrict__ x_in,
    const float* __restrict__ w1_0, const float* __restrict__ b1_0,
    const float* __restrict__ w1_1, const float* __restrict__ b1_1,
    const float* __restrict__ w1_2, const float* __restrict__ b1_2,
    const float* __restrict__ w2_0, const float* __restrict__ b2_0,
    const float* __restrict__ w2_1, const float* __restrict__ b2_1,
    const float* __restrict__ w2_2, const float* __restrict__ b2_2,
    const float* __restrict__ w3_0, const float* __restrict__ b3_0,
    const float* __restrict__ w3_1, const float* __restrict__ b3_1,
    const float* __restrict__ w3_2, const float* __restrict__ b3_2,
    float* __restrict__ out) {
    __shared__ int sCls[128];
    __shared__ int sRaw[128];
    __shared__ int sPerm[128];
    __shared__ int sCnt[192];
    __shared__ int sScan[192];
    __shared__ int sOffs[192];

    const int h = blockIdx.x >> 2;
    const int base = (blockIdx.x & 3) << 7;   // 0,128,256,384 within the line
    const int t = threadIdx.x;
    const int half = t & 1;
    const int px = t >> 1;                    // 0..127 (pair lanes 2px,2px+1 in same wave)
    const size_t rowoff = (size_t)h * WW + base;

    // ---- stage 1: per-line weights, 2 lanes per pixel ----
    {
        float xfull[32];
#pragma unroll
        for (int c = 0; c < 32; c++) xfull[c] = x_in[(size_t)c * NPIX + rowoff + px];
        float yh[16];
        layer_oi_h32(w1_0 + (size_t)h * 1024, b1_0 + (size_t)h * 32, half, xfull, yh);
#pragma unroll
        for (int k = 0; k < 16; k++) yh[k] = lrelu(yh[k]);
        exchange16(half, yh, xfull);
        layer_oi_h32(w1_1 + (size_t)h * 1024, b1_1 + (size_t)h * 32, half, xfull, yh);
#pragma unroll
        for (int k = 0; k < 16; k++) yh[k] = lrelu(yh[k]);
        exchange16(half, yh, xfull);
        float zh[8];
        layer_oi_h16(w1_2 + (size_t)h * 512, b1_2 + (size_t)h * 16, half, xfull, zh);
        float z[16];
        exchange8(half, zh, z);
        Res r = argmax_ent16(z);
        if (!half) {
            out[NPIX + rowoff + px] = r.ent;  // e1
            sCls[px] = r.idx;                 // inds1 in [0,16)
        }
    }
    if (t < 16) sCnt[t] = 0;
    __syncthreads();

    // ---- counting sort by inds1 (16 bins, 128 pixels) ----
    int rank = 0;
    if (t < 128) rank = atomicAdd(&sCnt[sCls[t]], 1);
    __syncthreads();
    if (t < 16) {
        int v = sCnt[t];
        int incl = v;
#pragma unroll
        for (int d = 1; d < 16; d <<= 1) {
            int n = __shfl_up(incl, d, 64);
            if (t >= d) incl += n;
        }
        sOffs[t] = incl - v;
    }
    __syncthreads();
    if (t < 128) sPerm[sOffs[sCls[t]] + rank] = t;
    __syncthreads();

    // ---- stage 2: sorted order, 2 lanes per pixel ----
    {
        int p = sPerm[px];
        int c1 = sCls[p];
        size_t e = (size_t)h * 16 + c1;
        Res r = expert_mlp_half(x_in + (size_t)32 * NPIX + rowoff, p, half,
                                w2_0, b2_0, w2_1, b2_1, w2_2, b2_2, e);
        int raw = c1 * 12 + r.idx - 2;       // inds12 (unclipped)
        if (!half) {
            out[2 * NPIX + rowoff + p] = r.ent;  // e2
            sRaw[p] = raw;
            int cl = raw < 0 ? 0 : (raw > 191 ? 191 : raw);
            sCls[p] = cl;  // own pixel slot only -> no race
        }
    }
    if (t < 192) sCnt[t] = 0;
    __syncthreads();

    // ---- counting sort by clipped inds12 (192 bins, 128 pixels) ----
    if (t < 128) rank = atomicAdd(&sCnt[sCls[t]], 1);
    __syncthreads();
    if (t < 192) {
        int v = sCnt[t];
        int incl = v;
#pragma unroll
        for (int d = 1; d < 64; d <<= 1) {
            int n = __shfl_up(incl, d, 64);
            if ((t & 63) >= d) incl += n;
        }
        sScan[t] = incl;
    }
    __syncthreads();
    if (t < 192) {
        int add = 0;
        if (t >= 64) add += sScan[63];
        if (t >= 128) add += sScan[127];
        sOffs[t] = sScan[t] + add - sCnt[t];
    }
    __syncthreads();
    if (t < 128) sPerm[sOffs[sCls[t]] + rank] = t;
    __syncthreads();

    // ---- stage 3: sorted order, 2 lanes per pixel ----
    {
        int p = sPerm[px];
        int cl = sCls[p];
        int raw = sRaw[p];
        size_t e = (size_t)h * 192 + cl;
        Res r = expert_mlp_half(x_in + (size_t)64 * NPIX + rowoff, p, half,
                                w3_0, b3_0, w3_1, b3_1, w3_2, b3_2, e);
        if (!half) {
            out[3 * NPIX + rowoff + p] = r.ent;  // e3
            int i123 = raw * 8 + r.idx - 4;
            i123 = i123 < 0 ? 0 : (i123 > 1535 ? 1535 : i123);
            out[rowoff + p] = (float)i123;       // inds123 as float
        }
    }
}

extern "C" void kernel_launch(void* const* d_in, const int* in_sizes, int n_in,
                              void* d_out, int out_size, void* d_ws, size_t ws_size,
                              hipStream_t stream) {
    const float* P[19];
    for (int i = 0; i < 19 && i < n_in; i++) P[i] = (const float*)d_in[i];

    const float *x_in, *W1[3], *B1[3], *W2[3], *B2[3], *W3[3], *B3[3];
    x_in = P[0];
    bool dict_order = (in_sizes[2] == 448 * 32);
    if (dict_order) {
        W1[0] = P[1];  B1[0] = P[2];  W1[1] = P[3];  B1[1] = P[4];  W1[2] = P[5];  B1[2] = P[6];
        W2[0] = P[7];  B2[0] = P[8];  W2[1] = P[9];  B2[1] = P[10]; W2[2] = P[11]; B2[2] = P[12];
        W3[0] = P[13]; B3[0] = P[14]; W3[1] = P[15]; B3[1] = P[16]; W3[2] = P[17]; B3[2] = P[18];
    } else {
        W1[0] = P[1];  W1[1] = P[2];  W1[2] = P[3];  B1[0] = P[4];  B1[1] = P[5];  B1[2] = P[6];
        W2[0] = P[7];  W2[1] = P[8];  W2[2] = P[9];  B2[0] = P[10]; B2[1] = P[11]; B2[2] = P[12];
        W3[0] = P[13]; W3[1] = P[14]; W3[2] = P[15]; B3[0] = P[16]; B3[1] = P[17]; B3[2] = P[18];
    }

    float* out = (float*)d_out;
    hipLaunchKernelGGL(cls3_kernel, dim3(4 * HH), dim3(256), 0, stream,
                       x_in,
                       W1[0], B1[0], W1[1], B1[1], W1[2], B1[2],
                       W2[0], B2[0], W2[1], B2[1], W2[2], B2[2],
                       W3[0], B3[0], W3[1], B3[1], W3[2], B3[2],
                       out);
}

// Round 12
// 201.481 us; speedup vs baseline: 1.7283x; 1.7283x over previous
//
#include <hip/hip_runtime.h>

#define HH 448
#define WW 512
#define NPIX (HH * WW)

struct Res { int idx; float ent; };

__device__ __forceinline__ float lrelu(float v) { return v > 0.0f ? v : 0.01f * v; }

__device__ __forceinline__ Res argmax_ent16(const float* __restrict__ v) {
    float m = v[0]; int idx = 0;
#pragma unroll
    for (int i = 1; i < 16; i++) { if (v[i] > m) { m = v[i]; idx = i; } }
    float s = 0.0f, dot = 0.0f;
#pragma unroll
    for (int i = 0; i < 16; i++) {
        float t = __expf(v[i] - m);
        s += t;
        dot = fmaf(t, v[i], dot);
    }
    Res r; r.idx = idx; r.ent = m + __logf(s) - dot / s;
    return r;
}

// NPX pixels, weight layout [in=32][OUT] (stages 2/3). Per-pixel fma order identical
// to the 1-pixel version (bitwise-stable). One weight float4 feeds 4*NPX fmas.
template <int NPX, int OUT>
__device__ __forceinline__ void layer_ioN(const float* __restrict__ w,
                                          const float* __restrict__ b,
                                          const float* __restrict__ x,
                                          float* __restrict__ y) {
    float acc[NPX][OUT];
#pragma unroll
    for (int n = 0; n < NPX; n++)
#pragma unroll
        for (int o = 0; o < OUT; o++) acc[n][o] = b[o];
#pragma unroll
    for (int i = 0; i < 32; i++) {
        const float4* row = (const float4*)(w + i * OUT);
#pragma unroll
        for (int q = 0; q < OUT / 4; q++) {
            float4 wv = row[q];
#pragma unroll
            for (int n = 0; n < NPX; n++) {
                float xi = x[n * 32 + i];
                acc[n][4 * q + 0] = fmaf(xi, wv.x, acc[n][4 * q + 0]);
                acc[n][4 * q + 1] = fmaf(xi, wv.y, acc[n][4 * q + 1]);
                acc[n][4 * q + 2] = fmaf(xi, wv.z, acc[n][4 * q + 2]);
                acc[n][4 * q + 3] = fmaf(xi, wv.w, acc[n][4 * q + 3]);
            }
        }
    }
#pragma unroll
    for (int n = 0; n < NPX; n++)
#pragma unroll
        for (int o = 0; o < OUT; o++) y[n * 32 + o] = acc[n][o];
}

// NPX pixels, weight layout [OUT][in=32] (stage 1, per-line uniform weights).
template <int NPX, int OUT>
__device__ __forceinline__ void layer_oiN(const float* __restrict__ w,
                                          const float* __restrict__ b,
                                          const float* __restrict__ x,
                                          float* __restrict__ y) {
#pragma unroll
    for (int o = 0; o < OUT; o++) {
        const float4* row = (const float4*)(w + o * 32);
        float a[NPX];
#pragma unroll
        for (int n = 0; n < NPX; n++) a[n] = b[o];
#pragma unroll
        for (int q = 0; q < 8; q++) {
            float4 wv = row[q];
#pragma unroll
            for (int n = 0; n < NPX; n++) {
                a[n] = fmaf(wv.x, x[n * 32 + 4 * q + 0], a[n]);
                a[n] = fmaf(wv.y, x[n * 32 + 4 * q + 1], a[n]);
                a[n] = fmaf(wv.z, x[n * 32 + 4 * q + 2], a[n]);
                a[n] = fmaf(wv.w, x[n * 32 + 4 * q + 3], a[n]);
            }
        }
#pragma unroll
        for (int n = 0; n < NPX; n++) y[n * 32 + o] = a[n];
    }
}

// 2-pixel expert MLP 32->32->32->16, shared expert e (per-lane global weights).
__device__ __forceinline__ void expert_mlp2(const float* __restrict__ xb,
                                            const int* __restrict__ p,
                                            const float* __restrict__ w0, const float* __restrict__ b0,
                                            const float* __restrict__ w1, const float* __restrict__ b1,
                                            const float* __restrict__ w2, const float* __restrict__ b2,
                                            size_t e, Res* __restrict__ r) {
    float x[64], y[64];
#pragma unroll
    for (int n = 0; n < 2; n++)
#pragma unroll
        for (int c = 0; c < 32; c++) x[n * 32 + c] = xb[(size_t)c * NPIX + p[n]];
    layer_ioN<2, 32>(w0 + e * 1024, b0 + e * 32, x, y);
#pragma unroll
    for (int k = 0; k < 64; k++) y[k] = lrelu(y[k]);
    layer_ioN<2, 32>(w1 + e * 1024, b1 + e * 32, y, x);
#pragma unroll
    for (int k = 0; k < 64; k++) x[k] = lrelu(x[k]);
    layer_ioN<2, 16>(w2 + e * 512, b2 + e * 16, x, y);
    r[0] = argmax_ent16(y);
    r[1] = argmax_ent16(y + 32);
}

__global__ __launch_bounds__(128, 2) void cls3_kernel(
    const float* __restrict__ x_in,
    const float* __restrict__ w1_0, const float* __restrict__ b1_0,
    const float* __restrict__ w1_1, const float* __restrict__ b1_1,
    const float* __restrict__ w1_2, const float* __restrict__ b1_2,
    const float* __restrict__ w2_0, const float* __restrict__ b2_0,
    const float* __restrict__ w2_1, const float* __restrict__ b2_1,
    const float* __restrict__ w2_2, const float* __restrict__ b2_2,
    const float* __restrict__ w3_0, const float* __restrict__ b3_0,
    const float* __restrict__ w3_1, const float* __restrict__ b3_1,
    const float* __restrict__ w3_2, const float* __restrict__ b3_2,
    float* __restrict__ out) {
    __shared__ int sCls[256];
    __shared__ int sRaw[256];
    __shared__ int sPerm[512];   // even-aligned slots (<=448 used)
    __shared__ int sCnt[192];
    __shared__ int sScan[192];
    __shared__ int sOffs[192];
    __shared__ int sTot;

    const int h = blockIdx.x >> 1;
    const int base = (blockIdx.x & 1) << 8;   // 0 or 256 within the line
    const int t = threadIdx.x;                 // 0..127
    const size_t rowoff = (size_t)h * WW + base;

    // ---- stage 1: 2 px/thread (t, t+128), per-line uniform weights ----
    {
        float x[64], y[64];
#pragma unroll
        for (int c = 0; c < 32; c++) {
            x[c]      = x_in[(size_t)c * NPIX + rowoff + t];
            x[32 + c] = x_in[(size_t)c * NPIX + rowoff + t + 128];
        }
        layer_oiN<2, 32>(w1_0 + (size_t)h * 1024, b1_0 + (size_t)h * 32, x, y);
#pragma unroll
        for (int k = 0; k < 64; k++) y[k] = lrelu(y[k]);
        layer_oiN<2, 32>(w1_1 + (size_t)h * 1024, b1_1 + (size_t)h * 32, y, x);
#pragma unroll
        for (int k = 0; k < 64; k++) x[k] = lrelu(x[k]);
        layer_oiN<2, 16>(w1_2 + (size_t)h * 512, b1_2 + (size_t)h * 16, x, y);
        Res r0 = argmax_ent16(y);
        Res r1 = argmax_ent16(y + 32);
        out[NPIX + rowoff + t] = r0.ent;          // e1
        out[NPIX + rowoff + t + 128] = r1.ent;
        sCls[t] = r0.idx;
        sCls[t + 128] = r1.idx;
    }
    if (t < 16) sCnt[t] = 0;
    __syncthreads();

    // ---- counting sort by inds1 (16 bins, even-aligned segments) ----
    int rkA = atomicAdd(&sCnt[sCls[t]], 1);
    int rkB = atomicAdd(&sCnt[sCls[t + 128]], 1);
    __syncthreads();
    if (t < 16) {
        int ce = (sCnt[t] + 1) & ~1;
        int incl = ce;
#pragma unroll
        for (int d = 1; d < 16; d <<= 1) {
            int n = __shfl_up(incl, d, 64);
            if (t >= d) incl += n;
        }
        sOffs[t] = incl - ce;
        if (t == 15) sTot = incl;
    }
    __syncthreads();
    sPerm[sOffs[sCls[t]] + rkA] = t;
    sPerm[sOffs[sCls[t + 128]] + rkB] = t + 128;
    __syncthreads();
    if (t < 16 && (sCnt[t] & 1)) {   // duplicate last pixel of odd segments
        int g = sOffs[t] + sCnt[t];
        sPerm[g] = sPerm[g - 1];
    }
    __syncthreads();

    // ---- stage 2: same-expert pairs ----
    {
        const int P = sTot >> 1;
        const float* xb = x_in + (size_t)32 * NPIX + rowoff;
        for (int j = t; j < P; j += 128) {
            int pp[2] = { sPerm[2 * j], sPerm[2 * j + 1] };
            int c1 = sCls[pp[0]];
            Res rr[2];
            expert_mlp2(xb, pp, w2_0, b2_0, w2_1, b2_1, w2_2, b2_2,
                        (size_t)h * 16 + c1, rr);
#pragma unroll
            for (int n = 0; n < 2; n++) {
                int q = pp[n];
                out[2 * NPIX + rowoff + q] = rr[n].ent;   // e2
                int raw = c1 * 12 + rr[n].idx - 2;
                sRaw[q] = raw;
                int cl = raw < 0 ? 0 : (raw > 191 ? 191 : raw);
                sCls[q] = cl;   // own pair's pixels only (dup writes same value)
            }
        }
    }
    __syncthreads();
    sCnt[t] = 0;
    if (t < 64) sCnt[128 + t] = 0;
    __syncthreads();

    // ---- counting sort by clipped inds12 (192 bins, even-aligned segments) ----
    rkA = atomicAdd(&sCnt[sCls[t]], 1);
    rkB = atomicAdd(&sCnt[sCls[t + 128]], 1);
    __syncthreads();
    {
        int lane = t & 63;
        if (t < 64) {
            int ce = (sCnt[lane] + 1) & ~1;
            int incl = ce;
#pragma unroll
            for (int d = 1; d < 64; d <<= 1) {
                int n = __shfl_up(incl, d, 64);
                if (lane >= d) incl += n;
            }
            sScan[lane] = incl;
            int ce2 = (sCnt[128 + lane] + 1) & ~1;
            int incl2 = ce2;
#pragma unroll
            for (int d = 1; d < 64; d <<= 1) {
                int n = __shfl_up(incl2, d, 64);
                if (lane >= d) incl2 += n;
            }
            sScan[128 + lane] = incl2;
        } else {
            int ce = (sCnt[64 + lane] + 1) & ~1;
            int incl = ce;
#pragma unroll
            for (int d = 1; d < 64; d <<= 1) {
                int n = __shfl_up(incl, d, 64);
                if (lane >= d) incl += n;
            }
            sScan[64 + lane] = incl;
        }
    }
    __syncthreads();
    {
        int ce = (sCnt[t] + 1) & ~1;
        sOffs[t] = sScan[t] - ce + (t >= 64 ? sScan[63] : 0);
        if (t < 64) {
            int b2 = 128 + t;
            int ce2 = (sCnt[b2] + 1) & ~1;
            sOffs[b2] = sScan[b2] - ce2 + sScan[63] + sScan[127];
        }
        if (t == 0) sTot = sScan[63] + sScan[127] + sScan[191];
    }
    __syncthreads();
    sPerm[sOffs[sCls[t]] + rkA] = t;
    sPerm[sOffs[sCls[t + 128]] + rkB] = t + 128;
    __syncthreads();
    {
        if (sCnt[t] & 1) { int g = sOffs[t] + sCnt[t]; sPerm[g] = sPerm[g - 1]; }
        if (t < 64) {
            int b2 = 128 + t;
            if (sCnt[b2] & 1) { int g = sOffs[b2] + sCnt[b2]; sPerm[g] = sPerm[g - 1]; }
        }
    }
    __syncthreads();

    // ---- stage 3: same-expert pairs ----
    {
        const int P = sTot >> 1;
        const float* xb = x_in + (size_t)64 * NPIX + rowoff;
        for (int j = t; j < P; j += 128) {
            int pp[2] = { sPerm[2 * j], sPerm[2 * j + 1] };
            int cl = sCls[pp[0]];
            Res rr[2];
            expert_mlp2(xb, pp, w3_0, b3_0, w3_1, b3_1, w3_2, b3_2,
                        (size_t)h * 192 + cl, rr);
#pragma unroll
            for (int n = 0; n < 2; n++) {
                int q = pp[n];
                int raw = sRaw[q];
                out[3 * NPIX + rowoff + q] = rr[n].ent;   // e3
                int i123 = raw * 8 + rr[n].idx - 4;
                i123 = i123 < 0 ? 0 : (i123 > 1535 ? 1535 : i123);
                out[rowoff + q] = (float)i123;            // inds123 as float
            }
        }
    }
}

extern "C" void kernel_launch(void* const* d_in, const int* in_sizes, int n_in,
                              void* d_out, int out_size, void* d_ws, size_t ws_size,
                              hipStream_t stream) {
    const float* P[19];
    for (int i = 0; i < 19 && i < n_in; i++) P[i] = (const float*)d_in[i];

    const float *x_in, *W1[3], *B1[3], *W2[3], *B2[3], *W3[3], *B3[3];
    x_in = P[0];
    bool dict_order = (in_sizes[2] == 448 * 32);
    if (dict_order) {
        W1[0] = P[1];  B1[0] = P[2];  W1[1] = P[3];  B1[1] = P[4];  W1[2] = P[5];  B1[2] = P[6];
        W2[0] = P[7];  B2[0] = P[8];  W2[1] = P[9];  B2[1] = P[10]; W2[2] = P[11]; B2[2] = P[12];
        W3[0] = P[13]; B3[0] = P[14]; W3[1] = P[15]; B3[1] = P[16]; W3[2] = P[17]; B3[2] = P[18];
    } else {
        W1[0] = P[1];  W1[1] = P[2];  W1[2] = P[3];  B1[0] = P[4];  B1[1] = P[5];  B1[2] = P[6];
        W2[0] = P[7];  W2[1] = P[8];  W2[2] = P[9];  B2[0] = P[10]; B2[1] = P[11]; B2[2] = P[12];
        W3[0] = P[13]; W3[1] = P[14]; W3[2] = P[15]; B3[0] = P[16]; B3[1] = P[17]; B3[2] = P[18];
    }

    float* out = (float*)d_out;
    hipLaunchKernelGGL(cls3_kernel, dim3(2 * HH), dim3(128), 0, stream,
                       x_in,
                       W1[0], B1[0], W1[1], B1[1], W1[2], B1[2],
                       W2[0], B2[0], W2[1], B2[1], W2[2], B2[2],
                       W3[0], B3[0], W3[1], B3[1], W3[2], B3[2],
                       out);
}

// Round 15
// 197.518 us; speedup vs baseline: 1.7629x; 1.0201x over previous
//
#include <hip/hip_runtime.h>

#define HH 448
#define WW 512
#define NPIX (HH * WW)

struct Res { int idx; float ent; };

__device__ __forceinline__ float lrelu(float v) { return v > 0.0f ? v : 0.01f * v; }

__device__ __forceinline__ Res argmax_ent16(const float* __restrict__ v) {
    float m = v[0]; int idx = 0;
#pragma unroll
    for (int i = 1; i < 16; i++) { if (v[i] > m) { m = v[i]; idx = i; } }
    float s = 0.0f, dot = 0.0f;
#pragma unroll
    for (int i = 0; i < 16; i++) {
        float t = __expf(v[i] - m);
        s += t;
        dot = fmaf(t, v[i], dot);
    }
    Res r; r.idx = idx; r.ent = m + __logf(s) - dot / s;
    return r;
}

// NPX pixels, weight layout [in=32][OUT] (stages 2/3). Per-pixel fma order identical
// to the 1-pixel version (bitwise-stable). One weight float4 feeds 4*NPX fmas.
template <int NPX, int OUT>
__device__ __forceinline__ void layer_ioN(const float* __restrict__ w,
                                          const float* __restrict__ b,
                                          const float* __restrict__ x,
                                          float* __restrict__ y) {
    float acc[NPX][OUT];
#pragma unroll
    for (int n = 0; n < NPX; n++)
#pragma unroll
        for (int o = 0; o < OUT; o++) acc[n][o] = b[o];
#pragma unroll
    for (int i = 0; i < 32; i++) {
        const float4* row = (const float4*)(w + i * OUT);
#pragma unroll
        for (int q = 0; q < OUT / 4; q++) {
            float4 wv = row[q];
#pragma unroll
            for (int n = 0; n < NPX; n++) {
                float xi = x[n * 32 + i];
                acc[n][4 * q + 0] = fmaf(xi, wv.x, acc[n][4 * q + 0]);
                acc[n][4 * q + 1] = fmaf(xi, wv.y, acc[n][4 * q + 1]);
                acc[n][4 * q + 2] = fmaf(xi, wv.z, acc[n][4 * q + 2]);
                acc[n][4 * q + 3] = fmaf(xi, wv.w, acc[n][4 * q + 3]);
            }
        }
    }
#pragma unroll
    for (int n = 0; n < NPX; n++)
#pragma unroll
        for (int o = 0; o < OUT; o++) y[n * 32 + o] = acc[n][o];
}

// NPX pixels, weight layout [OUT][in=32] (stage 1, per-line uniform weights).
template <int NPX, int OUT>
__device__ __forceinline__ void layer_oiN(const float* __restrict__ w,
                                          const float* __restrict__ b,
                                          const float* __restrict__ x,
                                          float* __restrict__ y) {
#pragma unroll
    for (int o = 0; o < OUT; o++) {
        const float4* row = (const float4*)(w + o * 32);
        float a[NPX];
#pragma unroll
        for (int n = 0; n < NPX; n++) a[n] = b[o];
#pragma unroll
        for (int q = 0; q < 8; q++) {
            float4 wv = row[q];
#pragma unroll
            for (int n = 0; n < NPX; n++) {
                a[n] = fmaf(wv.x, x[n * 32 + 4 * q + 0], a[n]);
                a[n] = fmaf(wv.y, x[n * 32 + 4 * q + 1], a[n]);
                a[n] = fmaf(wv.z, x[n * 32 + 4 * q + 2], a[n]);
                a[n] = fmaf(wv.w, x[n * 32 + 4 * q + 3], a[n]);
            }
        }
#pragma unroll
        for (int n = 0; n < NPX; n++) y[n * 32 + o] = a[n];
    }
}

// 2-pixel expert MLP 32->32->32->16, shared expert e (per-lane global weights).
__device__ __forceinline__ void expert_mlp2(const float* __restrict__ xb,
                                            const int* __restrict__ p,
                                            const float* __restrict__ w0, const float* __restrict__ b0,
                                            const float* __restrict__ w1, const float* __restrict__ b1,
                                            const float* __restrict__ w2, const float* __restrict__ b2,
                                            size_t e, Res* __restrict__ r) {
    float x[64], y[64];
#pragma unroll
    for (int n = 0; n < 2; n++)
#pragma unroll
        for (int c = 0; c < 32; c++) x[n * 32 + c] = xb[(size_t)c * NPIX + p[n]];
    layer_ioN<2, 32>(w0 + e * 1024, b0 + e * 32, x, y);
#pragma unroll
    for (int k = 0; k < 64; k++) y[k] = lrelu(y[k]);
    layer_ioN<2, 32>(w1 + e * 1024, b1 + e * 32, y, x);
#pragma unroll
    for (int k = 0; k < 64; k++) x[k] = lrelu(x[k]);
    layer_ioN<2, 16>(w2 + e * 512, b2 + e * 16, x, y);
    r[0] = argmax_ent16(y);
    r[1] = argmax_ent16(y + 32);
}

__global__ __launch_bounds__(128, 2) void cls3_kernel(
    const float* __restrict__ x_in,
    const float* __restrict__ w1_0, const float* __restrict__ b1_0,
    const float* __restrict__ w1_1, const float* __restrict__ b1_1,
    const float* __restrict__ w1_2, const float* __restrict__ b1_2,
    const float* __restrict__ w2_0, const float* __restrict__ b2_0,
    const float* __restrict__ w2_1, const float* __restrict__ b2_1,
    const float* __restrict__ w2_2, const float* __restrict__ b2_2,
    const float* __restrict__ w3_0, const float* __restrict__ b3_0,
    const float* __restrict__ w3_1, const float* __restrict__ b3_1,
    const float* __restrict__ w3_2, const float* __restrict__ b3_2,
    float* __restrict__ out) {
    __shared__ int sCls[256];
    __shared__ int sRaw[256];
    __shared__ int sPerm[512];   // even-aligned slots (<=448 used)
    __shared__ int sCnt[192];
    __shared__ int sScan[192];
    __shared__ int sOffs[192];
    __shared__ int sTot;

    // XCD-pair swizzle: both half-line blocks of line h land on the same XCD
    // (blockIdx round-robins across 8 XCDs; 896 = 8 * 112, 56 lines per XCD).
    const int bid = blockIdx.x;
    const int xcd = bid & 7;
    const int idx = bid >> 3;            // 0..111
    const int h = xcd * 56 + (idx >> 1); // 0..447
    const int base = (idx & 1) << 8;     // 0 or 256 within the line
    const int t = threadIdx.x;           // 0..127
    const size_t rowoff = (size_t)h * WW + base;

    // ---- stage 1: 2 px/thread (t, t+128), per-line uniform weights ----
    {
        float x[64], y[64];
#pragma unroll
        for (int c = 0; c < 32; c++) {
            x[c]      = x_in[(size_t)c * NPIX + rowoff + t];
            x[32 + c] = x_in[(size_t)c * NPIX + rowoff + t + 128];
        }
        layer_oiN<2, 32>(w1_0 + (size_t)h * 1024, b1_0 + (size_t)h * 32, x, y);
#pragma unroll
        for (int k = 0; k < 64; k++) y[k] = lrelu(y[k]);
        layer_oiN<2, 32>(w1_1 + (size_t)h * 1024, b1_1 + (size_t)h * 32, y, x);
#pragma unroll
        for (int k = 0; k < 64; k++) x[k] = lrelu(x[k]);
        layer_oiN<2, 16>(w1_2 + (size_t)h * 512, b1_2 + (size_t)h * 16, x, y);
        Res r0 = argmax_ent16(y);
        Res r1 = argmax_ent16(y + 32);
        out[NPIX + rowoff + t] = r0.ent;          // e1
        out[NPIX + rowoff + t + 128] = r1.ent;
        sCls[t] = r0.idx;
        sCls[t + 128] = r1.idx;
    }
    if (t < 16) sCnt[t] = 0;
    __syncthreads();

    // ---- counting sort by inds1 (16 bins, even-aligned segments) ----
    int rkA = atomicAdd(&sCnt[sCls[t]], 1);
    int rkB = atomicAdd(&sCnt[sCls[t + 128]], 1);
    __syncthreads();
    if (t < 16) {
        int ce = (sCnt[t] + 1) & ~1;
        int incl = ce;
#pragma unroll
        for (int d = 1; d < 16; d <<= 1) {
            int n = __shfl_up(incl, d, 64);
            if (t >= d) incl += n;
        }
        sOffs[t] = incl - ce;
        if (t == 15) sTot = incl;
    }
    __syncthreads();
    sPerm[sOffs[sCls[t]] + rkA] = t;
    sPerm[sOffs[sCls[t + 128]] + rkB] = t + 128;
    __syncthreads();
    if (t < 16 && (sCnt[t] & 1)) {   // duplicate last pixel of odd segments
        int g = sOffs[t] + sCnt[t];
        sPerm[g] = sPerm[g - 1];
    }
    __syncthreads();

    // ---- stage 2: same-expert pairs ----
    {
        const int P = sTot >> 1;
        const float* xb = x_in + (size_t)32 * NPIX + rowoff;
        for (int j = t; j < P; j += 128) {
            int pp[2] = { sPerm[2 * j], sPerm[2 * j + 1] };
            int c1 = sCls[pp[0]];
            Res rr[2];
            expert_mlp2(xb, pp, w2_0, b2_0, w2_1, b2_1, w2_2, b2_2,
                        (size_t)h * 16 + c1, rr);
#pragma unroll
            for (int n = 0; n < 2; n++) {
                int q = pp[n];
                out[2 * NPIX + rowoff + q] = rr[n].ent;   // e2
                int raw = c1 * 12 + rr[n].idx - 2;
                sRaw[q] = raw;
                int cl = raw < 0 ? 0 : (raw > 191 ? 191 : raw);
                sCls[q] = cl;   // own pair's pixels only (dup writes same value)
            }
        }
    }
    __syncthreads();
    sCnt[t] = 0;
    if (t < 64) sCnt[128 + t] = 0;
    __syncthreads();

    // ---- counting sort by clipped inds12 (192 bins, even-aligned segments) ----
    rkA = atomicAdd(&sCnt[sCls[t]], 1);
    rkB = atomicAdd(&sCnt[sCls[t + 128]], 1);
    __syncthreads();
    {
        int lane = t & 63;
        if (t < 64) {
            int ce = (sCnt[lane] + 1) & ~1;
            int incl = ce;
#pragma unroll
            for (int d = 1; d < 64; d <<= 1) {
                int n = __shfl_up(incl, d, 64);
                if (lane >= d) incl += n;
            }
            sScan[lane] = incl;
            int ce2 = (sCnt[128 + lane] + 1) & ~1;
            int incl2 = ce2;
#pragma unroll
            for (int d = 1; d < 64; d <<= 1) {
                int n = __shfl_up(incl2, d, 64);
                if (lane >= d) incl2 += n;
            }
            sScan[128 + lane] = incl2;
        } else {
            int ce = (sCnt[64 + lane] + 1) & ~1;
            int incl = ce;
#pragma unroll
            for (int d = 1; d < 64; d <<= 1) {
                int n = __shfl_up(incl, d, 64);
                if (lane >= d) incl += n;
            }
            sScan[64 + lane] = incl;
        }
    }
    __syncthreads();
    {
        int ce = (sCnt[t] + 1) & ~1;
        sOffs[t] = sScan[t] - ce + (t >= 64 ? sScan[63] : 0);
        if (t < 64) {
            int b2 = 128 + t;
            int ce2 = (sCnt[b2] + 1) & ~1;
            sOffs[b2] = sScan[b2] - ce2 + sScan[63] + sScan[127];
        }
        if (t == 0) sTot = sScan[63] + sScan[127] + sScan[191];
    }
    __syncthreads();
    sPerm[sOffs[sCls[t]] + rkA] = t;
    sPerm[sOffs[sCls[t + 128]] + rkB] = t + 128;
    __syncthreads();
    {
        if (sCnt[t] & 1) { int g = sOffs[t] + sCnt[t]; sPerm[g] = sPerm[g - 1]; }
        if (t < 64) {
            int b2 = 128 + t;
            if (sCnt[b2] & 1) { int g = sOffs[b2] + sCnt[b2]; sPerm[g] = sPerm[g - 1]; }
        }
    }
    __syncthreads();

    // ---- stage 3: same-expert pairs ----
    {
        const int P = sTot >> 1;
        const float* xb = x_in + (size_t)64 * NPIX + rowoff;
        for (int j = t; j < P; j += 128) {
            int pp[2] = { sPerm[2 * j], sPerm[2 * j + 1] };
            int cl = sCls[pp[0]];
            Res rr[2];
            expert_mlp2(xb, pp, w3_0, b3_0, w3_1, b3_1, w3_2, b3_2,
                        (size_t)h * 192 + cl, rr);
#pragma unroll
            for (int n = 0; n < 2; n++) {
                int q = pp[n];
                int raw = sRaw[q];
                out[3 * NPIX + rowoff + q] = rr[n].ent;   // e3
                int i123 = raw * 8 + rr[n].idx - 4;
                i123 = i123 < 0 ? 0 : (i123 > 1535 ? 1535 : i123);
                out[rowoff + q] = (float)i123;            // inds123 as float
            }
        }
    }
}

extern "C" void kernel_launch(void* const* d_in, const int* in_sizes, int n_in,
                              void* d_out, int out_size, void* d_ws, size_t ws_size,
                              hipStream_t stream) {
    const float* P[19];
    for (int i = 0; i < 19 && i < n_in; i++) P[i] = (const float*)d_in[i];

    const float *x_in, *W1[3], *B1[3], *W2[3], *B2[3], *W3[3], *B3[3];
    x_in = P[0];
    bool dict_order = (in_sizes[2] == 448 * 32);
    if (dict_order) {
        W1[0] = P[1];  B1[0] = P[2];  W1[1] = P[3];  B1[1] = P[4];  W1[2] = P[5];  B1[2] = P[6];
        W2[0] = P[7];  B2[0] = P[8];  W2[1] = P[9];  B2[1] = P[10]; W2[2] = P[11]; B2[2] = P[12];
        W3[0] = P[13]; B3[0] = P[14]; W3[1] = P[15]; B3[1] = P[16]; W3[2] = P[17]; B3[2] = P[18];
    } else {
        W1[0] = P[1];  W1[1] = P[2];  W1[2] = P[3];  B1[0] = P[4];  B1[1] = P[5];  B1[2] = P[6];
        W2[0] = P[7];  W2[1] = P[8];  W2[2] = P[9];  B2[0] = P[10]; B2[1] = P[11]; B2[2] = P[12];
        W3[0] = P[13]; W3[1] = P[14]; W3[2] = P[15]; B3[0] = P[16]; B3[1] = P[17]; B3[2] = P[18];
    }

    float* out = (float*)d_out;
    hipLaunchKernelGGL(cls3_kernel, dim3(2 * HH), dim3(128), 0, stream,
                       x_in,
                       W1[0], B1[0], W1[1], B1[1], W1[2], B1[2],
                       W2[0], B2[0], W2[1], B2[1], W2[2], B2[2],
                       W3[0], B3[0], W3[1], B3[1], W3[2], B3[2],
                       out);
}